// Round 11
// baseline (292.937 us; speedup 1.0000x reference)
//
#include <hip/hip_runtime.h>
#include <math.h>

#define N_NODES 50000
#define MPAD    50048   // round up to 64-row GEMM tiles
#define DEG     16
#define BATCH   1024
#define F_IN    128
#define HID     128
#define F_OUT   64
#define FE_H    8
#define FN_H    128
#define GP_H    128
#define E_TOT   (N_NODES * DEG)
#define GEMM1_BLOCKS (MPAD / 64)            // 782
#define EDGE_BLOCKS  ((E_TOT + 255) / 256)  // 3125
#define AGG_BLOCKS   (MPAD / 64)            // 782
#define STRUCT_BLOCKS (BATCH / 2)           // 512 (2 edges per block)

typedef __attribute__((ext_vector_type(8))) short          bf16x8;
typedef __attribute__((ext_vector_type(8))) unsigned short u16x8;
typedef __attribute__((ext_vector_type(4))) float          f32x4;
typedef unsigned long long u64;

__device__ __forceinline__ unsigned short f2bf(float f) {
    unsigned int u = __builtin_bit_cast(unsigned int, f);
    u += 0x7FFFu + ((u >> 16) & 1u);   // round-to-nearest-even
    return (unsigned short)(u >> 16);
}
__device__ __forceinline__ float bf2f(unsigned short s) {
    unsigned int u = ((unsigned int)s) << 16;
    return __builtin_bit_cast(float, u);
}
__device__ __forceinline__ float pdeg(u64 p) {   // d = 1 + count
    return 1.0f + (float)(unsigned int)(p >> 32);
}

// ---------------------------------------------------------------------------
// 1. prep: zero packed + feat + ticket, convert W1/W2/W3 -> transposed bf16
// ---------------------------------------------------------------------------
__global__ void k_prep(u64* __restrict__ packed, float* __restrict__ feat,
                       unsigned int* __restrict__ ticket,
                       const float* __restrict__ W1, const float* __restrict__ W2,
                       const float* __restrict__ W3, unsigned short* __restrict__ Wt1,
                       unsigned short* __restrict__ Wt2, unsigned short* __restrict__ Wt3) {
    int idx = blockIdx.x * blockDim.x + threadIdx.x;
    if (idx < MPAD) packed[idx] = 0ull;
    if (idx < F_OUT) feat[idx] = 0.0f;
    if (idx == 0) *ticket = 0u;
    if (idx < 16384) {
        int k = idx >> 7, c = idx & 127;
        Wt1[c * 128 + k] = f2bf(W1[idx]);
    } else if (idx < 32768) {
        int t = idx - 16384; int k = t >> 7, c = t & 127;
        Wt2[c * 128 + k] = f2bf(W2[t]);
    } else if (idx < 40960) {
        int t = idx - 32768; int k = t >> 6, c = t & 63;
        Wt3[c * 128 + k] = f2bf(W3[t]);
    }
}

// ---------------------------------------------------------------------------
// 2. FUSED: layer-1 GEMM ∥ edge packed-atomic scatter (proven 47us floor).
// ---------------------------------------------------------------------------
__global__ __launch_bounds__(256) void k_gemm1_edge(
    const float* __restrict__ x, const unsigned short* __restrict__ Wt,
    unsigned short* __restrict__ t,
    const int* __restrict__ nbr, const float* __restrict__ A_w,
    const float* __restrict__ fe_w1, const float* __restrict__ fe_b1,
    const float* __restrict__ fe_w2, const float* __restrict__ fe_b2,
    u64* __restrict__ packed) {
    if (blockIdx.x < GEMM1_BLOCKS) {
        int lane = threadIdx.x & 63;
        int wave = threadIdx.x >> 6;
        int row_in = lane & 15;
        int kb = lane >> 4;                      // 0..3
        int r0 = blockIdx.x * 64 + wave * 16;
        int r  = min(r0 + row_in, N_NODES - 1);  // clamp: no OOB read of x
        f32x4 acc[8];
#pragma unroll
        for (int ct = 0; ct < 8; ++ct) acc[ct] = (f32x4){0.f, 0.f, 0.f, 0.f};
#pragma unroll
        for (int ks = 0; ks < 4; ++ks) {
            const float4* xr = (const float4*)(x + r * 128 + ks * 32 + kb * 8);
            float4 p0 = xr[0], p1 = xr[1];
            bf16x8 a;
            a[0] = (short)f2bf(p0.x); a[1] = (short)f2bf(p0.y);
            a[2] = (short)f2bf(p0.z); a[3] = (short)f2bf(p0.w);
            a[4] = (short)f2bf(p1.x); a[5] = (short)f2bf(p1.y);
            a[6] = (short)f2bf(p1.z); a[7] = (short)f2bf(p1.w);
#pragma unroll
            for (int ct = 0; ct < 8; ++ct) {
                bf16x8 b = *(const bf16x8*)(Wt + (ct * 16 + row_in) * 128 + ks * 32 + kb * 8);
                acc[ct] = __builtin_amdgcn_mfma_f32_16x16x32_bf16(a, b, acc[ct], 0, 0, 0);
            }
        }
#pragma unroll
        for (int ct = 0; ct < 8; ++ct)
#pragma unroll
            for (int rr = 0; rr < 4; ++rr)
                t[(r0 + kb * 4 + rr) * 128 + ct * 16 + row_in] = f2bf(acc[ct][rr]);
    } else {
        int e = (blockIdx.x - GEMM1_BLOCKS) * 256 + threadIdx.x;
        if (e >= E_TOT) return;
        int   c = nbr[e];
        float v = A_w[e];
        float acc = fe_b2[0];
#pragma unroll
        for (int j = 0; j < FE_H; ++j) {
            float hj = fmaf(v, fe_w1[j], fe_b1[j]);
            acc = fmaf(fmaxf(hj, 0.0f), fe_w2[j], acc);
        }
        // fixed-point: bias 32, scale 2^19 (32*2^19 = 2^24 exactly)
        int fx = (int)rintf(fmaf(acc, 524288.0f, 16777216.0f));
        atomicAdd(&packed[c], (1ull << 32) + (u64)(unsigned int)fx);
    }
}

// ---------------------------------------------------------------------------
// 3. FUSED agg(relu)+GEMM  [+ optional struct-pre tail blocks]
//    Slim LDS (~22KB): ls + s_w only -> 7 blocks/CU ceiling for the
//    latency-bound random gather. nbr read direct (L1 broadcast).
// ---------------------------------------------------------------------------
template <int OUTC, bool WITH_STRUCT>
__global__ __launch_bounds__(256) void k_agg_gemm(
    const unsigned short* __restrict__ t, const int* __restrict__ nbr,
    const u64* __restrict__ packed, const float* __restrict__ bias,
    const unsigned short* __restrict__ Wt, unsigned short* __restrict__ tout,
    const int* __restrict__ edge, const float* __restrict__ A_w,
    const float* __restrict__ fn_w1, const float* __restrict__ fn_b1,
    const float* __restrict__ fn_w2, const float* __restrict__ fn_b2,
    const float* __restrict__ gp_w1, const float* __restrict__ gp_b1,
    const float* __restrict__ gp_w2, const float* __restrict__ gp_b2,
    float* __restrict__ sigraw, float* __restrict__ out) {
    __shared__ unsigned short ls[64][136];   // +8 pad: 272B row stride
    __shared__ float s_w[64][DEG];
    __shared__ float wv[2][32];
    __shared__ int   nv[2][32];
    __shared__ float red[2][2];
    __shared__ float red2[2][2];
    const int tid = threadIdx.x;

    if (!WITH_STRUCT || blockIdx.x < AGG_BLOCKS) {
        const int base = blockIdx.x * 64;
        for (int q = tid; q < 64 * DEG; q += 256) {
            int row = q >> 4, k = q & 15;
            int ii = min(base + row, N_NODES - 1);
            int j = nbr[ii * DEG + k];
            s_w[row][k] = rsqrtf(pdeg(packed[ii]) * pdeg(packed[j]));  // ref rsqrt(d_i*d_j)
        }
        __syncthreads();
        const int g = tid >> 4, sub = tid & 15;
        const u16x8* t8 = (const u16x8*)t;
        float4 b0 = ((const float4*)bias)[sub * 2];
        float4 b1 = ((const float4*)bias)[sub * 2 + 1];
        float bv[8] = {b0.x, b0.y, b0.z, b0.w, b1.x, b1.y, b1.z, b1.w};
#pragma unroll
        for (int r = 0; r < 4; ++r) {
            int row = r * 16 + g;
            int ii  = min(base + row, N_NODES - 1);
            const int* nrow = nbr + ii * DEG;
            // prefetch all DEG neighbor fragments (ILP: 16 loads in flight)
            u16x8 vb[DEG];
#pragma unroll
            for (int k = 0; k < DEG; ++k) vb[k] = t8[nrow[k] * 16 + sub];
            float si = 1.0f / pdeg(packed[ii]);
            u16x8 tv = t8[ii * 16 + sub];
            float acc[8];
#pragma unroll
            for (int c = 0; c < 8; ++c) acc[c] = fmaf(bf2f((unsigned short)tv[c]), si, bv[c]);
#pragma unroll
            for (int k = 0; k < DEG; ++k) {
                float w = s_w[row][k];
#pragma unroll
                for (int c = 0; c < 8; ++c) acc[c] = fmaf(w, bf2f((unsigned short)vb[k][c]), acc[c]);
            }
            u16x8 o;
#pragma unroll
            for (int c = 0; c < 8; ++c) o[c] = f2bf(fmaxf(acc[c], 0.0f));
            *(u16x8*)(&ls[row][sub * 8]) = o;
        }
        __syncthreads();
        int lane = tid & 63, wave = tid >> 6;
        int row_in = lane & 15, kb = lane >> 4;
        int lrow = wave * 16 + row_in;
        f32x4 acc2[OUTC / 16];
#pragma unroll
        for (int ct = 0; ct < OUTC / 16; ++ct) acc2[ct] = (f32x4){0.f, 0.f, 0.f, 0.f};
#pragma unroll
        for (int ks = 0; ks < 4; ++ks) {
            bf16x8 a = *(const bf16x8*)(&ls[lrow][ks * 32 + kb * 8]);
#pragma unroll
            for (int ct = 0; ct < OUTC / 16; ++ct) {
                bf16x8 b = *(const bf16x8*)(Wt + (ct * 16 + row_in) * 128 + ks * 32 + kb * 8);
                acc2[ct] = __builtin_amdgcn_mfma_f32_16x16x32_bf16(a, b, acc2[ct], 0, 0, 0);
            }
        }
#pragma unroll
        for (int ct = 0; ct < OUTC / 16; ++ct)
#pragma unroll
            for (int rr = 0; rr < 4; ++rr)
                tout[(base + wave * 16 + kb * 4 + rr) * OUTC + ct * 16 + row_in] = f2bf(acc2[ct][rr]);
    } else {
        // ---- struct-pre: 2 batch edges per block, 128 threads each ----
        int half = tid >> 7;                 // 0 or 1
        int l    = tid & 127;
        int b    = (blockIdx.x - AGG_BLOCKS) * 2 + half;
        int e = l >> 2, sub = l & 3;
        int which = e >> 4, k = e & 15;
        int ref  = edge[which * BATCH + b];
        int node = nbr[ref * DEG + k];
        u64  p   = packed[node];
        unsigned int cnt = (unsigned int)(p >> 32);
        long long noBias = (long long)(p & 0xFFFFFFFFull) - ((long long)cnt << 24);
        float v = (float)noBias * (1.0f / 524288.0f);    // nsf[node]
        float part = 0.0f;
#pragma unroll
        for (int jj = 0; jj < FN_H / 4; ++jj) {
            int j = sub * (FN_H / 4) + jj;
            float hj = fmaf(v, fn_w1[j], fn_b1[j]);
            part = fmaf(fmaxf(hj, 0.0f), fn_w2[j], part);
        }
        part += __shfl_xor(part, 1);
        part += __shfl_xor(part, 2);
        if (sub == 0) {
            wv[half][e] = A_w[ref * DEG + k] * (part + fn_b2[0]);
            nv[half][e] = node;
        }
        __syncthreads();
        float ps = 0.0f;
        {
            int p2 = l, i0 = p2 >> 4, j0 = p2 & 15;
            if (nv[half][i0] == nv[half][16 + j0]) ps += wv[half][i0] * wv[half][16 + j0];
            p2 = l + 128; i0 = p2 >> 4; j0 = p2 & 15;
            if (nv[half][i0] == nv[half][16 + j0]) ps += wv[half][i0] * wv[half][16 + j0];
        }
        for (int off = 1; off < 64; off <<= 1) ps += __shfl_xor(ps, off);
        if ((l & 63) == 0) red[half][l >> 6] = ps;
        __syncthreads();
        float os = red[half][0] + red[half][1];

        float hj = fmaf(os, gp_w1[l], gp_b1[l]);
        float g  = fmaxf(hj, 0.0f) * gp_w2[l];
        for (int off = 1; off < 64; off <<= 1) g += __shfl_xor(g, off);
        if ((l & 63) == 0) red2[half][l >> 6] = g;
        __syncthreads();
        float raw = red2[half][0] + red2[half][1] + gp_b2[0];
        float sig = 1.0f / (1.0f + expf(-raw));
        if (l == 0) {
            sigraw[b] = sig;
            out[BATCH * F_OUT + b] = sig;                          // out_struct_sig
            out[BATCH * F_OUT + BATCH + F_OUT + b] = raw;          // out_struct_raw
        }
    }
}

// ---------------------------------------------------------------------------
// 4. final aggregate (64 cols, no relu), inline deg decode + prefetch
// ---------------------------------------------------------------------------
__global__ __launch_bounds__(256) void k_agg64(const unsigned short* __restrict__ t,
                                               const int* __restrict__ nbr,
                                               const u64* __restrict__ packed,
                                               const float* __restrict__ bias,
                                               unsigned short* __restrict__ hout) {
    constexpr int TPN = 8;            // threads per node (16B each)
    constexpr int NPB = 32;           // nodes per block
    __shared__ int   s_nb[NPB][DEG];
    __shared__ float s_w[NPB][DEG];
    __shared__ float s_idg[NPB];
    int g   = threadIdx.x / TPN;
    int sub = threadIdx.x % TPN;
    int i   = blockIdx.x * NPB + g;
    bool ok = (i < N_NODES);
    if (ok) {
        float di = pdeg(packed[i]);
        if (sub == 0) s_idg[g] = 1.0f / di;
        for (int k = sub; k < DEG; k += TPN) {
            int j = nbr[i * DEG + k];
            s_nb[g][k] = j;
            s_w[g][k]  = rsqrtf(di * pdeg(packed[j]));
        }
    }
    __syncthreads();
    if (!ok) return;
    const u16x8* t8 = (const u16x8*)t;
    float si = s_idg[g];
    float4 b0 = ((const float4*)bias)[sub * 2];
    float4 b1 = ((const float4*)bias)[sub * 2 + 1];
    float bv[8] = {b0.x, b0.y, b0.z, b0.w, b1.x, b1.y, b1.z, b1.w};
    u16x8 vb[DEG];
#pragma unroll
    for (int k = 0; k < DEG; ++k) vb[k] = t8[s_nb[g][k] * TPN + sub];
    u16x8 tv = t8[i * TPN + sub];
    float acc[8];
#pragma unroll
    for (int c = 0; c < 8; ++c) acc[c] = fmaf(bf2f((unsigned short)tv[c]), si, bv[c]);
#pragma unroll
    for (int k = 0; k < DEG; ++k) {
        float w = s_w[g][k];
#pragma unroll
        for (int c = 0; c < 8; ++c) acc[c] = fmaf(w, bf2f((unsigned short)vb[k][c]), acc[c]);
    }
    u16x8 o;
#pragma unroll
    for (int c = 0; c < 8; ++c) o[c] = f2bf(acc[c]);
    ((u16x8*)hout)[i * TPN + sub] = o;
}

// ---------------------------------------------------------------------------
// 5. feat + finish (ticket): out_feat reduction, last block blends outputs
// ---------------------------------------------------------------------------
__global__ __launch_bounds__(64) void k_feat_finish(
    const unsigned short* __restrict__ h3, const int* __restrict__ edge,
    float* __restrict__ feat, unsigned int* __restrict__ ticket,
    const float* __restrict__ sigraw, const float* __restrict__ alpha,
    float* __restrict__ out) {
    int c = threadIdx.x;  // 0..63
    float acc = 0.0f;
    for (int b = blockIdx.x; b < BATCH; b += gridDim.x) {
        int s = edge[b];
        int d = edge[BATCH + b];
        acc = fmaf(bf2f(h3[s * F_OUT + c]), bf2f(h3[d * F_OUT + c]), acc);
    }
    atomicAdd(&feat[c], acc);
    __threadfence();
    __shared__ unsigned int done;
    if (c == 0) done = atomicAdd(ticket, 1u);
    __syncthreads();
    if (done == 255u) {                       // last of 256 blocks
        __threadfence();
        float fv = feat[c];
        float a0e = alpha[0], a1e = alpha[1];
        float m  = fmaxf(a0e, a1e);
        float e0 = expf(a0e - m), e1 = expf(a1e - m);
        float inv = 1.0f / (e0 + e1);
        float a0 = e0 * inv, a1 = e1 * inv;
        for (int b = 0; b < BATCH; ++b)
            out[b * F_OUT + c] = fmaf(a1, fv, a0 * sigraw[b]) + 1e-15f;
        out[BATCH * F_OUT + BATCH + c] = fv;  // out_feat
    }
}

// ---------------------------------------------------------------------------
extern "C" void kernel_launch(void* const* d_in, const int* in_sizes, int n_in,
                              void* d_out, int out_size, void* d_ws, size_t ws_size,
                              hipStream_t stream) {
    const int*   edge  = (const int*)d_in[0];
    const float* x     = (const float*)d_in[1];
    const int*   nbr   = (const int*)d_in[2];
    const float* A_w   = (const float*)d_in[3];
    const float* W1    = (const float*)d_in[4];
    const float* b1    = (const float*)d_in[5];
    const float* W2    = (const float*)d_in[6];
    const float* b2    = (const float*)d_in[7];
    const float* W3    = (const float*)d_in[8];
    const float* b3    = (const float*)d_in[9];
    const float* fe_w1 = (const float*)d_in[10];
    const float* fe_b1 = (const float*)d_in[11];
    const float* fe_w2 = (const float*)d_in[12];
    const float* fe_b2 = (const float*)d_in[13];
    const float* fn_w1 = (const float*)d_in[14];
    const float* fn_b1 = (const float*)d_in[15];
    const float* fn_w2 = (const float*)d_in[16];
    const float* fn_b2 = (const float*)d_in[17];
    const float* gp_w1 = (const float*)d_in[18];
    const float* gp_b1 = (const float*)d_in[19];
    const float* gp_w2 = (const float*)d_in[20];
    const float* gp_b2 = (const float*)d_in[21];
    const float* alpha = (const float*)d_in[22];

    char* w = (char*)d_ws;
    u64*   packed = (u64*)w;                         // MPAD*8 = 400384 B
    float* feat   = (float*)(w + 400384);            // 64 f32
    float* sigraw = feat + 64;                       // 1024 f32
    unsigned int* ticket = (unsigned int*)(sigraw + 1024);
    unsigned short* tA  = (unsigned short*)(w + 400384 + 8192);     // MPAD*128 bf16
    unsigned short* tB  = tA + (size_t)MPAD * 128;                  // MPAD*128 bf16
    unsigned short* Wt1 = tB + (size_t)MPAD * 128;                  // 128*128
    unsigned short* Wt2 = Wt1 + 128 * 128;                          // 128*128
    unsigned short* Wt3 = Wt2 + 128 * 128;                          // 64*128
    float* out  = (float*)d_out;

    k_prep<<<(MPAD + 255) / 256, 256, 0, stream>>>(packed, feat, ticket, W1, W2, W3,
                                                   Wt1, Wt2, Wt3);
    // layer-1 GEMM ∥ edge scatter (packed global atomics — proven floor)
    k_gemm1_edge<<<GEMM1_BLOCKS + EDGE_BLOCKS, 256, 0, stream>>>(
        x, Wt1, tA, nbr, A_w, fe_w1, fe_b1, fe_w2, fe_b2, packed);
    // layer 2 = agg1 + gemm2  ∥  struct-pre (sig/raw per batch edge)
    k_agg_gemm<128, true><<<AGG_BLOCKS + STRUCT_BLOCKS, 256, 0, stream>>>(
        tA, nbr, packed, b1, Wt2, tB,
        edge, A_w, fn_w1, fn_b1, fn_w2, fn_b2,
        gp_w1, gp_b1, gp_w2, gp_b2, sigraw, out);
    // layer 3 = agg2 + gemm3
    k_agg_gemm<64, false><<<AGG_BLOCKS, 256, 0, stream>>>(
        tB, nbr, packed, b2, Wt3, tA,
        nullptr, nullptr, nullptr, nullptr, nullptr, nullptr,
        nullptr, nullptr, nullptr, nullptr, nullptr, nullptr);
    // final aggregate (no relu)
    k_agg64<<<(N_NODES + 31) / 32, 256, 0, stream>>>(tA, nbr, packed, b3, tB);
    // out_feat reduction + last-block final blend
    k_feat_finish<<<256, 64, 0, stream>>>(tB, edge, feat, ticket, sigraw, alpha, out);
}

// Round 12
// 268.596 us; speedup vs baseline: 1.0906x; 1.0906x over previous
//
#include <hip/hip_runtime.h>
#include <math.h>

#define N_NODES 50000
#define MPAD    50048   // round up to 64-row GEMM tiles
#define DEG     16
#define BATCH   1024
#define F_IN    128
#define HID     128
#define F_OUT   64
#define FE_H    8
#define FN_H    128
#define GP_H    128
#define E_TOT   (N_NODES * DEG)
#define GEMM1_BLOCKS (MPAD / 64)            // 782
#define EDGE_BLOCKS  ((E_TOT + 255) / 256)  // 3125
#define AGG_BLOCKS   (MPAD / 64)            // 782
#define STRUCT_BLOCKS (BATCH / 2)           // 512 (2 edges per block)
#define FEAT_EPB     2                      // edges per k_feat2 block
#define FEAT_BLOCKS  (BATCH / FEAT_EPB)     // 512

typedef __attribute__((ext_vector_type(8))) short          bf16x8;
typedef __attribute__((ext_vector_type(8))) unsigned short u16x8;
typedef __attribute__((ext_vector_type(4))) float          f32x4;
typedef unsigned long long u64;

__device__ __forceinline__ unsigned short f2bf(float f) {
    unsigned int u = __builtin_bit_cast(unsigned int, f);
    u += 0x7FFFu + ((u >> 16) & 1u);   // round-to-nearest-even
    return (unsigned short)(u >> 16);
}
__device__ __forceinline__ float bf2f(unsigned short s) {
    unsigned int u = ((unsigned int)s) << 16;
    return __builtin_bit_cast(float, u);
}
__device__ __forceinline__ float pdeg(u64 p) {   // d = 1 + count
    return 1.0f + (float)(unsigned int)(p >> 32);
}

// ---------------------------------------------------------------------------
// 1. prep: zero packed + feat, convert W1/W2/W3 -> transposed bf16
// ---------------------------------------------------------------------------
__global__ void k_prep(u64* __restrict__ packed, float* __restrict__ feat,
                       const float* __restrict__ W1, const float* __restrict__ W2,
                       const float* __restrict__ W3, unsigned short* __restrict__ Wt1,
                       unsigned short* __restrict__ Wt2, unsigned short* __restrict__ Wt3) {
    int idx = blockIdx.x * blockDim.x + threadIdx.x;
    if (idx < MPAD) packed[idx] = 0ull;
    if (idx < F_OUT) feat[idx] = 0.0f;
    if (idx < 16384) {
        int k = idx >> 7, c = idx & 127;
        Wt1[c * 128 + k] = f2bf(W1[idx]);
    } else if (idx < 32768) {
        int t = idx - 16384; int k = t >> 7, c = t & 127;
        Wt2[c * 128 + k] = f2bf(W2[t]);
    } else if (idx < 40960) {
        int t = idx - 32768; int k = t >> 6, c = t & 63;
        Wt3[c * 128 + k] = f2bf(W3[t]);
    }
}

// ---------------------------------------------------------------------------
// 2. FUSED: layer-1 GEMM ∥ edge packed-atomic scatter (proven 47us floor).
// ---------------------------------------------------------------------------
__global__ __launch_bounds__(256) void k_gemm1_edge(
    const float* __restrict__ x, const unsigned short* __restrict__ Wt,
    unsigned short* __restrict__ t,
    const int* __restrict__ nbr, const float* __restrict__ A_w,
    const float* __restrict__ fe_w1, const float* __restrict__ fe_b1,
    const float* __restrict__ fe_w2, const float* __restrict__ fe_b2,
    u64* __restrict__ packed) {
    if (blockIdx.x < GEMM1_BLOCKS) {
        int lane = threadIdx.x & 63;
        int wave = threadIdx.x >> 6;
        int row_in = lane & 15;
        int kb = lane >> 4;                      // 0..3
        int r0 = blockIdx.x * 64 + wave * 16;
        int r  = min(r0 + row_in, N_NODES - 1);  // clamp: no OOB read of x
        f32x4 acc[8];
#pragma unroll
        for (int ct = 0; ct < 8; ++ct) acc[ct] = (f32x4){0.f, 0.f, 0.f, 0.f};
#pragma unroll
        for (int ks = 0; ks < 4; ++ks) {
            const float4* xr = (const float4*)(x + r * 128 + ks * 32 + kb * 8);
            float4 p0 = xr[0], p1 = xr[1];
            bf16x8 a;
            a[0] = (short)f2bf(p0.x); a[1] = (short)f2bf(p0.y);
            a[2] = (short)f2bf(p0.z); a[3] = (short)f2bf(p0.w);
            a[4] = (short)f2bf(p1.x); a[5] = (short)f2bf(p1.y);
            a[6] = (short)f2bf(p1.z); a[7] = (short)f2bf(p1.w);
#pragma unroll
            for (int ct = 0; ct < 8; ++ct) {
                bf16x8 b = *(const bf16x8*)(Wt + (ct * 16 + row_in) * 128 + ks * 32 + kb * 8);
                acc[ct] = __builtin_amdgcn_mfma_f32_16x16x32_bf16(a, b, acc[ct], 0, 0, 0);
            }
        }
#pragma unroll
        for (int ct = 0; ct < 8; ++ct)
#pragma unroll
            for (int rr = 0; rr < 4; ++rr)
                t[(r0 + kb * 4 + rr) * 128 + ct * 16 + row_in] = f2bf(acc[ct][rr]);
    } else {
        int e = (blockIdx.x - GEMM1_BLOCKS) * 256 + threadIdx.x;
        if (e >= E_TOT) return;
        int   c = nbr[e];
        float v = A_w[e];
        float acc = fe_b2[0];
#pragma unroll
        for (int j = 0; j < FE_H; ++j) {
            float hj = fmaf(v, fe_w1[j], fe_b1[j]);
            acc = fmaf(fmaxf(hj, 0.0f), fe_w2[j], acc);
        }
        // fixed-point: bias 32, scale 2^19 (32*2^19 = 2^24 exactly)
        int fx = (int)rintf(fmaf(acc, 524288.0f, 16777216.0f));
        atomicAdd(&packed[c], (1ull << 32) + (u64)(unsigned int)fx);
    }
}

// ---------------------------------------------------------------------------
// 3. FUSED agg(relu)+GEMM  [+ optional struct-pre tail blocks]
// ---------------------------------------------------------------------------
template <int OUTC, bool WITH_STRUCT>
__global__ __launch_bounds__(256) void k_agg_gemm(
    const unsigned short* __restrict__ t, const int* __restrict__ nbr,
    const u64* __restrict__ packed, const float* __restrict__ bias,
    const unsigned short* __restrict__ Wt, unsigned short* __restrict__ tout,
    const int* __restrict__ edge, const float* __restrict__ A_w,
    const float* __restrict__ fn_w1, const float* __restrict__ fn_b1,
    const float* __restrict__ fn_w2, const float* __restrict__ fn_b2,
    const float* __restrict__ gp_w1, const float* __restrict__ gp_b1,
    const float* __restrict__ gp_w2, const float* __restrict__ gp_b2,
    float* __restrict__ sigraw, float* __restrict__ out) {
    __shared__ unsigned short ls[64][136];   // +8 pad: 272B row stride
    __shared__ float s_w[64][DEG];
    __shared__ float wv[2][32];
    __shared__ int   nv[2][32];
    __shared__ float red[2][2];
    __shared__ float red2[2][2];
    const int tid = threadIdx.x;

    if (!WITH_STRUCT || blockIdx.x < AGG_BLOCKS) {
        const int base = blockIdx.x * 64;
        for (int q = tid; q < 64 * DEG; q += 256) {
            int row = q >> 4, k = q & 15;
            int ii = min(base + row, N_NODES - 1);
            int j = nbr[ii * DEG + k];
            s_w[row][k] = rsqrtf(pdeg(packed[ii]) * pdeg(packed[j]));  // ref rsqrt(d_i*d_j)
        }
        __syncthreads();
        const int g = tid >> 4, sub = tid & 15;
        const u16x8* t8 = (const u16x8*)t;
        float4 b0 = ((const float4*)bias)[sub * 2];
        float4 b1 = ((const float4*)bias)[sub * 2 + 1];
        float bv[8] = {b0.x, b0.y, b0.z, b0.w, b1.x, b1.y, b1.z, b1.w};
#pragma unroll
        for (int r = 0; r < 4; ++r) {
            int row = r * 16 + g;
            int ii  = min(base + row, N_NODES - 1);
            const int* nrow = nbr + ii * DEG;
            u16x8 vb[DEG];
#pragma unroll
            for (int k = 0; k < DEG; ++k) vb[k] = t8[nrow[k] * 16 + sub];
            float si = 1.0f / pdeg(packed[ii]);
            u16x8 tv = t8[ii * 16 + sub];
            float acc[8];
#pragma unroll
            for (int c = 0; c < 8; ++c) acc[c] = fmaf(bf2f((unsigned short)tv[c]), si, bv[c]);
#pragma unroll
            for (int k = 0; k < DEG; ++k) {
                float w = s_w[row][k];
#pragma unroll
                for (int c = 0; c < 8; ++c) acc[c] = fmaf(w, bf2f((unsigned short)vb[k][c]), acc[c]);
            }
            u16x8 o;
#pragma unroll
            for (int c = 0; c < 8; ++c) o[c] = f2bf(fmaxf(acc[c], 0.0f));
            *(u16x8*)(&ls[row][sub * 8]) = o;
        }
        __syncthreads();
        int lane = tid & 63, wave = tid >> 6;
        int row_in = lane & 15, kb = lane >> 4;
        int lrow = wave * 16 + row_in;
        f32x4 acc2[OUTC / 16];
#pragma unroll
        for (int ct = 0; ct < OUTC / 16; ++ct) acc2[ct] = (f32x4){0.f, 0.f, 0.f, 0.f};
#pragma unroll
        for (int ks = 0; ks < 4; ++ks) {
            bf16x8 a = *(const bf16x8*)(&ls[lrow][ks * 32 + kb * 8]);
#pragma unroll
            for (int ct = 0; ct < OUTC / 16; ++ct) {
                bf16x8 b = *(const bf16x8*)(Wt + (ct * 16 + row_in) * 128 + ks * 32 + kb * 8);
                acc2[ct] = __builtin_amdgcn_mfma_f32_16x16x32_bf16(a, b, acc2[ct], 0, 0, 0);
            }
        }
#pragma unroll
        for (int ct = 0; ct < OUTC / 16; ++ct)
#pragma unroll
            for (int rr = 0; rr < 4; ++rr)
                tout[(base + wave * 16 + kb * 4 + rr) * OUTC + ct * 16 + row_in] = f2bf(acc2[ct][rr]);
    } else {
        // ---- struct-pre: 2 batch edges per block, 128 threads each ----
        int half = tid >> 7;                 // 0 or 1
        int l    = tid & 127;
        int b    = (blockIdx.x - AGG_BLOCKS) * 2 + half;
        int e = l >> 2, sub = l & 3;
        int which = e >> 4, k = e & 15;
        int ref  = edge[which * BATCH + b];
        int node = nbr[ref * DEG + k];
        u64  p   = packed[node];
        unsigned int cnt = (unsigned int)(p >> 32);
        long long noBias = (long long)(p & 0xFFFFFFFFull) - ((long long)cnt << 24);
        float v = (float)noBias * (1.0f / 524288.0f);    // nsf[node]
        float part = 0.0f;
#pragma unroll
        for (int jj = 0; jj < FN_H / 4; ++jj) {
            int j = sub * (FN_H / 4) + jj;
            float hj = fmaf(v, fn_w1[j], fn_b1[j]);
            part = fmaf(fmaxf(hj, 0.0f), fn_w2[j], part);
        }
        part += __shfl_xor(part, 1);
        part += __shfl_xor(part, 2);
        if (sub == 0) {
            wv[half][e] = A_w[ref * DEG + k] * (part + fn_b2[0]);
            nv[half][e] = node;
        }
        __syncthreads();
        float ps = 0.0f;
        {
            int p2 = l, i0 = p2 >> 4, j0 = p2 & 15;
            if (nv[half][i0] == nv[half][16 + j0]) ps += wv[half][i0] * wv[half][16 + j0];
            p2 = l + 128; i0 = p2 >> 4; j0 = p2 & 15;
            if (nv[half][i0] == nv[half][16 + j0]) ps += wv[half][i0] * wv[half][16 + j0];
        }
        for (int off = 1; off < 64; off <<= 1) ps += __shfl_xor(ps, off);
        if ((l & 63) == 0) red[half][l >> 6] = ps;
        __syncthreads();
        float os = red[half][0] + red[half][1];

        float hj = fmaf(os, gp_w1[l], gp_b1[l]);
        float g  = fmaxf(hj, 0.0f) * gp_w2[l];
        for (int off = 1; off < 64; off <<= 1) g += __shfl_xor(g, off);
        if ((l & 63) == 0) red2[half][l >> 6] = g;
        __syncthreads();
        float raw = red2[half][0] + red2[half][1] + gp_b2[0];
        float sig = 1.0f / (1.0f + expf(-raw));
        if (l == 0) {
            sigraw[b] = sig;
            out[BATCH * F_OUT + b] = sig;                          // out_struct_sig
            out[BATCH * F_OUT + BATCH + F_OUT + b] = raw;          // out_struct_raw
        }
    }
}

// ---------------------------------------------------------------------------
// 4. feat2: on-the-fly h3 ONLY at edge endpoints (replaces full agg64+feat).
//    Wave w of the block handles endpoint w; lane c owns column c, so each
//    of the 17 row-reads is one coalesced 128B wave-load.
// ---------------------------------------------------------------------------
__global__ __launch_bounds__(128) void k_feat2(
    const unsigned short* __restrict__ t3, const int* __restrict__ nbr,
    const u64* __restrict__ packed, const int* __restrict__ edge,
    const float* __restrict__ b3, float* __restrict__ feat) {
    __shared__ float hs[2][F_OUT];
    int wave = threadIdx.x >> 6;     // endpoint select (src/dst)
    int lane = threadIdx.x & 63;     // column
    float accf = 0.0f;
#pragma unroll
    for (int i = 0; i < FEAT_EPB; ++i) {
        int b    = blockIdx.x * FEAT_EPB + i;
        int node = edge[wave * BATCH + b];
        float di = pdeg(packed[node]);
        // self + 16 neighbor rows, each a coalesced wave-load
        float acc = bf2f(t3[node * F_OUT + lane]) / di + b3[lane];
        const int* nrow = nbr + node * DEG;
#pragma unroll
        for (int k = 0; k < DEG; ++k) {
            int j = nrow[k];
            float w = rsqrtf(di * pdeg(packed[j]));
            acc = fmaf(w, bf2f(t3[j * F_OUT + lane]), acc);
        }
        hs[wave][lane] = acc;
        __syncthreads();
        if (wave == 0) accf = fmaf(hs[0][lane], hs[1][lane], accf);
        __syncthreads();
    }
    if (wave == 0) atomicAdd(&feat[lane], accf);
}

// ---------------------------------------------------------------------------
// 5. finish: out[b][c] = a0*sig[b] + a1*feat[c] + 1e-15 ; out_feat row
// ---------------------------------------------------------------------------
__global__ __launch_bounds__(64) void k_finish(const float* __restrict__ sigraw,
                                               const float* __restrict__ feat,
                                               const float* __restrict__ alpha,
                                               float* __restrict__ out) {
    int b = blockIdx.x, c = threadIdx.x;
    float a0e = alpha[0], a1e = alpha[1];
    float m  = fmaxf(a0e, a1e);
    float e0 = expf(a0e - m), e1 = expf(a1e - m);
    float inv = 1.0f / (e0 + e1);
    float a0 = e0 * inv, a1 = e1 * inv;
    float fv = feat[c];
    out[b * F_OUT + c] = fmaf(a1, fv, a0 * sigraw[b]) + 1e-15f;
    if (b == 0) out[BATCH * F_OUT + BATCH + c] = fv;           // out_feat
}

// ---------------------------------------------------------------------------
extern "C" void kernel_launch(void* const* d_in, const int* in_sizes, int n_in,
                              void* d_out, int out_size, void* d_ws, size_t ws_size,
                              hipStream_t stream) {
    const int*   edge  = (const int*)d_in[0];
    const float* x     = (const float*)d_in[1];
    const int*   nbr   = (const int*)d_in[2];
    const float* A_w   = (const float*)d_in[3];
    const float* W1    = (const float*)d_in[4];
    const float* b1    = (const float*)d_in[5];
    const float* W2    = (const float*)d_in[6];
    const float* b2    = (const float*)d_in[7];
    const float* W3    = (const float*)d_in[8];
    const float* b3    = (const float*)d_in[9];
    const float* fe_w1 = (const float*)d_in[10];
    const float* fe_b1 = (const float*)d_in[11];
    const float* fe_w2 = (const float*)d_in[12];
    const float* fe_b2 = (const float*)d_in[13];
    const float* fn_w1 = (const float*)d_in[14];
    const float* fn_b1 = (const float*)d_in[15];
    const float* fn_w2 = (const float*)d_in[16];
    const float* fn_b2 = (const float*)d_in[17];
    const float* gp_w1 = (const float*)d_in[18];
    const float* gp_b1 = (const float*)d_in[19];
    const float* gp_w2 = (const float*)d_in[20];
    const float* gp_b2 = (const float*)d_in[21];
    const float* alpha = (const float*)d_in[22];

    char* w = (char*)d_ws;
    u64*   packed = (u64*)w;                         // MPAD*8 = 400384 B
    float* feat   = (float*)(w + 400384);            // 64 f32
    float* sigraw = feat + 64;                       // 1024 f32
    unsigned short* tA  = (unsigned short*)(w + 400384 + 8192);     // MPAD*128 bf16
    unsigned short* tB  = tA + (size_t)MPAD * 128;                  // MPAD*128 bf16
    unsigned short* Wt1 = tB + (size_t)MPAD * 128;                  // 128*128
    unsigned short* Wt2 = Wt1 + 128 * 128;                          // 128*128
    unsigned short* Wt3 = Wt2 + 128 * 128;                          // 64*128
    float* out  = (float*)d_out;

    k_prep<<<(MPAD + 255) / 256, 256, 0, stream>>>(packed, feat, W1, W2, W3,
                                                   Wt1, Wt2, Wt3);
    // layer-1 GEMM ∥ edge scatter (packed global atomics — proven floor)
    k_gemm1_edge<<<GEMM1_BLOCKS + EDGE_BLOCKS, 256, 0, stream>>>(
        x, Wt1, tA, nbr, A_w, fe_w1, fe_b1, fe_w2, fe_b2, packed);
    // layer 2 = agg1 + gemm2  ∥  struct-pre (sig/raw per batch edge)
    k_agg_gemm<128, true><<<AGG_BLOCKS + STRUCT_BLOCKS, 256, 0, stream>>>(
        tA, nbr, packed, b1, Wt2, tB,
        edge, A_w, fn_w1, fn_b1, fn_w2, fn_b2,
        gp_w1, gp_b1, gp_w2, gp_b2, sigraw, out);
    // layer 3 = agg2 + gemm3  (t3 -> tA)
    k_agg_gemm<64, false><<<AGG_BLOCKS, 256, 0, stream>>>(
        tB, nbr, packed, b2, Wt3, tA,
        nullptr, nullptr, nullptr, nullptr, nullptr, nullptr,
        nullptr, nullptr, nullptr, nullptr, nullptr, nullptr);
    // out_feat: on-the-fly h3 at edge endpoints only (replaces agg64 + feat)
    k_feat2<<<FEAT_BLOCKS, 128, 0, stream>>>(tA, nbr, packed, edge, b3, feat);
    // final blend
    k_finish<<<BATCH, 64, 0, stream>>>(sigraw, feat, alpha, out);
}

// Round 13
// 250.369 us; speedup vs baseline: 1.1700x; 1.0728x over previous
//
#include <hip/hip_runtime.h>
#include <math.h>

#define N_NODES 50000
#define MPAD    50048   // round up to 32-row agg tiles & 64-row gemm1 tiles
#define DEG     16
#define BATCH   1024
#define F_IN    128
#define HID     128
#define F_OUT   64
#define FE_H    8
#define FN_H    128
#define GP_H    128
#define E_TOT   (N_NODES * DEG)
#define GEMM1_BLOCKS (MPAD / 64)            // 782
#define EDGE_BLOCKS  ((E_TOT + 255) / 256)  // 3125
#define AGG_BLOCKS   (MPAD / 32)            // 1564  (32-row tiles)
#define STRUCT_BLOCKS (BATCH / 2)           // 512 (2 edges per block)
#define FEAT_EPB     2                      // edges per k_feat2 block
#define FEAT_BLOCKS  (BATCH / FEAT_EPB)     // 512

typedef __attribute__((ext_vector_type(8))) short          bf16x8;
typedef __attribute__((ext_vector_type(8))) unsigned short u16x8;
typedef __attribute__((ext_vector_type(4))) float          f32x4;
typedef unsigned long long u64;

__device__ __forceinline__ unsigned short f2bf(float f) {
    unsigned int u = __builtin_bit_cast(unsigned int, f);
    u += 0x7FFFu + ((u >> 16) & 1u);   // round-to-nearest-even
    return (unsigned short)(u >> 16);
}
__device__ __forceinline__ float bf2f(unsigned short s) {
    unsigned int u = ((unsigned int)s) << 16;
    return __builtin_bit_cast(float, u);
}
__device__ __forceinline__ float pdeg(u64 p) {   // d = 1 + count
    return 1.0f + (float)(unsigned int)(p >> 32);
}

// ---------------------------------------------------------------------------
// 1. prep: zero packed + feat, convert W1/W2/W3 -> transposed bf16
// ---------------------------------------------------------------------------
__global__ void k_prep(u64* __restrict__ packed, float* __restrict__ feat,
                       const float* __restrict__ W1, const float* __restrict__ W2,
                       const float* __restrict__ W3, unsigned short* __restrict__ Wt1,
                       unsigned short* __restrict__ Wt2, unsigned short* __restrict__ Wt3) {
    int idx = blockIdx.x * blockDim.x + threadIdx.x;
    if (idx < MPAD) packed[idx] = 0ull;
    if (idx < F_OUT) feat[idx] = 0.0f;
    if (idx < 16384) {
        int k = idx >> 7, c = idx & 127;
        Wt1[c * 128 + k] = f2bf(W1[idx]);
    } else if (idx < 32768) {
        int t = idx - 16384; int k = t >> 7, c = t & 127;
        Wt2[c * 128 + k] = f2bf(W2[t]);
    } else if (idx < 40960) {
        int t = idx - 32768; int k = t >> 6, c = t & 63;
        Wt3[c * 128 + k] = f2bf(W3[t]);
    }
}

// ---------------------------------------------------------------------------
// 2. FUSED: layer-1 GEMM ∥ edge packed-atomic scatter (proven 47us floor).
// ---------------------------------------------------------------------------
__global__ __launch_bounds__(256) void k_gemm1_edge(
    const float* __restrict__ x, const unsigned short* __restrict__ Wt,
    unsigned short* __restrict__ t,
    const int* __restrict__ nbr, const float* __restrict__ A_w,
    const float* __restrict__ fe_w1, const float* __restrict__ fe_b1,
    const float* __restrict__ fe_w2, const float* __restrict__ fe_b2,
    u64* __restrict__ packed) {
    if (blockIdx.x < GEMM1_BLOCKS) {
        int lane = threadIdx.x & 63;
        int wave = threadIdx.x >> 6;
        int row_in = lane & 15;
        int kb = lane >> 4;                      // 0..3
        int r0 = blockIdx.x * 64 + wave * 16;
        int r  = min(r0 + row_in, N_NODES - 1);  // clamp: no OOB read of x
        f32x4 acc[8];
#pragma unroll
        for (int ct = 0; ct < 8; ++ct) acc[ct] = (f32x4){0.f, 0.f, 0.f, 0.f};
#pragma unroll
        for (int ks = 0; ks < 4; ++ks) {
            const float4* xr = (const float4*)(x + r * 128 + ks * 32 + kb * 8);
            float4 p0 = xr[0], p1 = xr[1];
            bf16x8 a;
            a[0] = (short)f2bf(p0.x); a[1] = (short)f2bf(p0.y);
            a[2] = (short)f2bf(p0.z); a[3] = (short)f2bf(p0.w);
            a[4] = (short)f2bf(p1.x); a[5] = (short)f2bf(p1.y);
            a[6] = (short)f2bf(p1.z); a[7] = (short)f2bf(p1.w);
#pragma unroll
            for (int ct = 0; ct < 8; ++ct) {
                bf16x8 b = *(const bf16x8*)(Wt + (ct * 16 + row_in) * 128 + ks * 32 + kb * 8);
                acc[ct] = __builtin_amdgcn_mfma_f32_16x16x32_bf16(a, b, acc[ct], 0, 0, 0);
            }
        }
#pragma unroll
        for (int ct = 0; ct < 8; ++ct)
#pragma unroll
            for (int rr = 0; rr < 4; ++rr)
                t[(r0 + kb * 4 + rr) * 128 + ct * 16 + row_in] = f2bf(acc[ct][rr]);
    } else {
        int e = (blockIdx.x - GEMM1_BLOCKS) * 256 + threadIdx.x;
        if (e >= E_TOT) return;
        int   c = nbr[e];
        float v = A_w[e];
        float acc = fe_b2[0];
#pragma unroll
        for (int j = 0; j < FE_H; ++j) {
            float hj = fmaf(v, fe_w1[j], fe_b1[j]);
            acc = fmaf(fmaxf(hj, 0.0f), fe_w2[j], acc);
        }
        // fixed-point: bias 32, scale 2^19 (32*2^19 = 2^24 exactly)
        int fx = (int)rintf(fmaf(acc, 524288.0f, 16777216.0f));
        atomicAdd(&packed[c], (1ull << 32) + (u64)(unsigned int)fx);
    }
}

// ---------------------------------------------------------------------------
// 3. FUSED agg(relu)+GEMM, 32-ROW TILES (2x grid vs 64-row: gather is
//    latency-bound at 12 waves/CU; 1564 blocks -> ~24 waves/CU).
//    GEMM phase: wave w = (row-half, col-half); 16 rows x OUTC/2 cols each.
//    [+ struct-pre tail blocks on the WITH_STRUCT launch]
// ---------------------------------------------------------------------------
template <int OUTC, bool WITH_STRUCT>
__global__ __launch_bounds__(256) void k_agg_gemm(
    const unsigned short* __restrict__ t, const int* __restrict__ nbr,
    const u64* __restrict__ packed, const float* __restrict__ bias,
    const unsigned short* __restrict__ Wt, unsigned short* __restrict__ tout,
    const int* __restrict__ edge, const float* __restrict__ A_w,
    const float* __restrict__ fn_w1, const float* __restrict__ fn_b1,
    const float* __restrict__ fn_w2, const float* __restrict__ fn_b2,
    const float* __restrict__ gp_w1, const float* __restrict__ gp_b1,
    const float* __restrict__ gp_w2, const float* __restrict__ gp_b2,
    float* __restrict__ sigraw, float* __restrict__ out) {
    __shared__ unsigned short ls[32][136];   // +8 pad: 272B row stride
    __shared__ float s_w[32][DEG];
    __shared__ float wv[2][32];
    __shared__ int   nv[2][32];
    __shared__ float red[2][2];
    __shared__ float red2[2][2];
    const int tid = threadIdx.x;

    if (!WITH_STRUCT || blockIdx.x < AGG_BLOCKS) {
        const int base = blockIdx.x * 32;
        for (int q = tid; q < 32 * DEG; q += 256) {
            int row = q >> 4, k = q & 15;
            int ii = min(base + row, N_NODES - 1);
            int j = nbr[ii * DEG + k];
            s_w[row][k] = rsqrtf(pdeg(packed[ii]) * pdeg(packed[j]));  // ref rsqrt(d_i*d_j)
        }
        __syncthreads();
        const int g = tid >> 4, sub = tid & 15;
        const u16x8* t8 = (const u16x8*)t;
        float4 b0 = ((const float4*)bias)[sub * 2];
        float4 b1 = ((const float4*)bias)[sub * 2 + 1];
        float bv[8] = {b0.x, b0.y, b0.z, b0.w, b1.x, b1.y, b1.z, b1.w};
#pragma unroll
        for (int r = 0; r < 2; ++r) {
            int row = r * 16 + g;
            int ii  = min(base + row, N_NODES - 1);
            const int* nrow = nbr + ii * DEG;
            u16x8 vb[DEG];
#pragma unroll
            for (int k = 0; k < DEG; ++k) vb[k] = t8[nrow[k] * 16 + sub];
            float si = 1.0f / pdeg(packed[ii]);
            u16x8 tv = t8[ii * 16 + sub];
            float acc[8];
#pragma unroll
            for (int c = 0; c < 8; ++c) acc[c] = fmaf(bf2f((unsigned short)tv[c]), si, bv[c]);
#pragma unroll
            for (int k = 0; k < DEG; ++k) {
                float w = s_w[row][k];
#pragma unroll
                for (int c = 0; c < 8; ++c) acc[c] = fmaf(w, bf2f((unsigned short)vb[k][c]), acc[c]);
            }
            u16x8 o;
#pragma unroll
            for (int c = 0; c < 8; ++c) o[c] = f2bf(fmaxf(acc[c], 0.0f));
            *(u16x8*)(&ls[row][sub * 8]) = o;
        }
        __syncthreads();
        int lane = tid & 63, wave = tid >> 6;
        int row_in = lane & 15, kb = lane >> 4;
        int rhalf = wave & 1, chalf = wave >> 1;
        constexpr int CPW = OUTC / 2;            // cols per wave
        int lrow = rhalf * 16 + row_in;
        f32x4 acc2[CPW / 16];
#pragma unroll
        for (int ct = 0; ct < CPW / 16; ++ct) acc2[ct] = (f32x4){0.f, 0.f, 0.f, 0.f};
#pragma unroll
        for (int ks = 0; ks < 4; ++ks) {
            bf16x8 a = *(const bf16x8*)(&ls[lrow][ks * 32 + kb * 8]);
#pragma unroll
            for (int ct = 0; ct < CPW / 16; ++ct) {
                bf16x8 b = *(const bf16x8*)(Wt + (chalf * CPW + ct * 16 + row_in) * 128 + ks * 32 + kb * 8);
                acc2[ct] = __builtin_amdgcn_mfma_f32_16x16x32_bf16(a, b, acc2[ct], 0, 0, 0);
            }
        }
#pragma unroll
        for (int ct = 0; ct < CPW / 16; ++ct)
#pragma unroll
            for (int rr = 0; rr < 4; ++rr)
                tout[(base + rhalf * 16 + kb * 4 + rr) * OUTC + chalf * CPW + ct * 16 + row_in] =
                    f2bf(acc2[ct][rr]);
    } else {
        // ---- struct-pre: 2 batch edges per block, 128 threads each ----
        int half = tid >> 7;                 // 0 or 1
        int l    = tid & 127;
        int b    = (blockIdx.x - AGG_BLOCKS) * 2 + half;
        int e = l >> 2, sub = l & 3;
        int which = e >> 4, k = e & 15;
        int ref  = edge[which * BATCH + b];
        int node = nbr[ref * DEG + k];
        u64  p   = packed[node];
        unsigned int cnt = (unsigned int)(p >> 32);
        long long noBias = (long long)(p & 0xFFFFFFFFull) - ((long long)cnt << 24);
        float v = (float)noBias * (1.0f / 524288.0f);    // nsf[node]
        float part = 0.0f;
#pragma unroll
        for (int jj = 0; jj < FN_H / 4; ++jj) {
            int j = sub * (FN_H / 4) + jj;
            float hj = fmaf(v, fn_w1[j], fn_b1[j]);
            part = fmaf(fmaxf(hj, 0.0f), fn_w2[j], part);
        }
        part += __shfl_xor(part, 1);
        part += __shfl_xor(part, 2);
        if (sub == 0) {
            wv[half][e] = A_w[ref * DEG + k] * (part + fn_b2[0]);
            nv[half][e] = node;
        }
        __syncthreads();
        float ps = 0.0f;
        {
            int p2 = l, i0 = p2 >> 4, j0 = p2 & 15;
            if (nv[half][i0] == nv[half][16 + j0]) ps += wv[half][i0] * wv[half][16 + j0];
            p2 = l + 128; i0 = p2 >> 4; j0 = p2 & 15;
            if (nv[half][i0] == nv[half][16 + j0]) ps += wv[half][i0] * wv[half][16 + j0];
        }
        for (int off = 1; off < 64; off <<= 1) ps += __shfl_xor(ps, off);
        if ((l & 63) == 0) red[half][l >> 6] = ps;
        __syncthreads();
        float os = red[half][0] + red[half][1];

        float hj = fmaf(os, gp_w1[l], gp_b1[l]);
        float g  = fmaxf(hj, 0.0f) * gp_w2[l];
        for (int off = 1; off < 64; off <<= 1) g += __shfl_xor(g, off);
        if ((l & 63) == 0) red2[half][l >> 6] = g;
        __syncthreads();
        float raw = red2[half][0] + red2[half][1] + gp_b2[0];
        float sig = 1.0f / (1.0f + expf(-raw));
        if (l == 0) {
            sigraw[b] = sig;
            out[BATCH * F_OUT + b] = sig;                          // out_struct_sig
            out[BATCH * F_OUT + BATCH + F_OUT + b] = raw;          // out_struct_raw
        }
    }
}

// ---------------------------------------------------------------------------
// 4. feat2: on-the-fly h3 ONLY at edge endpoints (no full-graph agg pass).
// ---------------------------------------------------------------------------
__global__ __launch_bounds__(128) void k_feat2(
    const unsigned short* __restrict__ t3, const int* __restrict__ nbr,
    const u64* __restrict__ packed, const int* __restrict__ edge,
    const float* __restrict__ b3, float* __restrict__ feat) {
    __shared__ float hs[2][F_OUT];
    int wave = threadIdx.x >> 6;     // endpoint select (src/dst)
    int lane = threadIdx.x & 63;     // column
    float accf = 0.0f;
#pragma unroll
    for (int i = 0; i < FEAT_EPB; ++i) {
        int b    = blockIdx.x * FEAT_EPB + i;
        int node = edge[wave * BATCH + b];
        float di = pdeg(packed[node]);
        float acc = bf2f(t3[node * F_OUT + lane]) / di + b3[lane];
        const int* nrow = nbr + node * DEG;
#pragma unroll
        for (int k = 0; k < DEG; ++k) {
            int j = nrow[k];
            float w = rsqrtf(di * pdeg(packed[j]));
            acc = fmaf(w, bf2f(t3[j * F_OUT + lane]), acc);
        }
        hs[wave][lane] = acc;
        __syncthreads();
        if (wave == 0) accf = fmaf(hs[0][lane], hs[1][lane], accf);
        __syncthreads();
    }
    if (wave == 0) atomicAdd(&feat[lane], accf);
}

// ---------------------------------------------------------------------------
// 5. finish: out[b][c] = a0*sig[b] + a1*feat[c] + 1e-15 ; out_feat row
// ---------------------------------------------------------------------------
__global__ __launch_bounds__(64) void k_finish(const float* __restrict__ sigraw,
                                               const float* __restrict__ feat,
                                               const float* __restrict__ alpha,
                                               float* __restrict__ out) {
    int b = blockIdx.x, c = threadIdx.x;
    float a0e = alpha[0], a1e = alpha[1];
    float m  = fmaxf(a0e, a1e);
    float e0 = expf(a0e - m), e1 = expf(a1e - m);
    float inv = 1.0f / (e0 + e1);
    float a0 = e0 * inv, a1 = e1 * inv;
    float fv = feat[c];
    out[b * F_OUT + c] = fmaf(a1, fv, a0 * sigraw[b]) + 1e-15f;
    if (b == 0) out[BATCH * F_OUT + BATCH + c] = fv;           // out_feat
}

// ---------------------------------------------------------------------------
extern "C" void kernel_launch(void* const* d_in, const int* in_sizes, int n_in,
                              void* d_out, int out_size, void* d_ws, size_t ws_size,
                              hipStream_t stream) {
    const int*   edge  = (const int*)d_in[0];
    const float* x     = (const float*)d_in[1];
    const int*   nbr   = (const int*)d_in[2];
    const float* A_w   = (const float*)d_in[3];
    const float* W1    = (const float*)d_in[4];
    const float* b1    = (const float*)d_in[5];
    const float* W2    = (const float*)d_in[6];
    const float* b2    = (const float*)d_in[7];
    const float* W3    = (const float*)d_in[8];
    const float* b3    = (const float*)d_in[9];
    const float* fe_w1 = (const float*)d_in[10];
    const float* fe_b1 = (const float*)d_in[11];
    const float* fe_w2 = (const float*)d_in[12];
    const float* fe_b2 = (const float*)d_in[13];
    const float* fn_w1 = (const float*)d_in[14];
    const float* fn_b1 = (const float*)d_in[15];
    const float* fn_w2 = (const float*)d_in[16];
    const float* fn_b2 = (const float*)d_in[17];
    const float* gp_w1 = (const float*)d_in[18];
    const float* gp_b1 = (const float*)d_in[19];
    const float* gp_w2 = (const float*)d_in[20];
    const float* gp_b2 = (const float*)d_in[21];
    const float* alpha = (const float*)d_in[22];

    char* w = (char*)d_ws;
    u64*   packed = (u64*)w;                         // MPAD*8 = 400384 B
    float* feat   = (float*)(w + 400384);            // 64 f32
    float* sigraw = feat + 64;                       // 1024 f32
    unsigned short* tA  = (unsigned short*)(w + 400384 + 8192);     // MPAD*128 bf16
    unsigned short* tB  = tA + (size_t)MPAD * 128;                  // MPAD*128 bf16
    unsigned short* Wt1 = tB + (size_t)MPAD * 128;                  // 128*128
    unsigned short* Wt2 = Wt1 + 128 * 128;                          // 128*128
    unsigned short* Wt3 = Wt2 + 128 * 128;                          // 64*128
    float* out  = (float*)d_out;

    k_prep<<<(MPAD + 255) / 256, 256, 0, stream>>>(packed, feat, W1, W2, W3,
                                                   Wt1, Wt2, Wt3);
    // layer-1 GEMM ∥ edge scatter (packed global atomics — proven floor)
    k_gemm1_edge<<<GEMM1_BLOCKS + EDGE_BLOCKS, 256, 0, stream>>>(
        x, Wt1, tA, nbr, A_w, fe_w1, fe_b1, fe_w2, fe_b2, packed);
    // layer 2 = agg1 + gemm2 (32-row tiles) ∥ struct-pre
    k_agg_gemm<128, true><<<AGG_BLOCKS + STRUCT_BLOCKS, 256, 0, stream>>>(
        tA, nbr, packed, b1, Wt2, tB,
        edge, A_w, fn_w1, fn_b1, fn_w2, fn_b2,
        gp_w1, gp_b1, gp_w2, gp_b2, sigraw, out);
    // layer 3 = agg2 + gemm3 (32-row tiles)  (t3 -> tA)
    k_agg_gemm<64, false><<<AGG_BLOCKS, 256, 0, stream>>>(
        tB, nbr, packed, b2, Wt3, tA,
        nullptr, nullptr, nullptr, nullptr, nullptr, nullptr,
        nullptr, nullptr, nullptr, nullptr, nullptr, nullptr);
    // out_feat: on-the-fly h3 at edge endpoints only
    k_feat2<<<FEAT_BLOCKS, 128, 0, stream>>>(tA, nbr, packed, edge, b3, feat);
    // final blend
    k_finish<<<BATCH, 64, 0, stream>>>(sigraw, feat, alpha, out);
}